// Round 9
// baseline (59.871 us; speedup 1.0000x reference)
//
#include <hip/hip_runtime.h>
#include <hip/hip_bf16.h>

#define NNODES 50000
#define NEDGES 200000
#define WCT_ROW 552                      // f16 units; 1104B row (pad vs 544 kills read conflicts)
#define WCT_BYTES (32 * WCT_ROW * 2)     // 35328
#define TILE_EDGES 64
#define NTILES (NEDGES / TILE_EDGES)     // 3125
#define WORK_BLOCKS 768                  // 3 blocks/CU (LDS-capped), grid-stride over tiles
#define DROW 36                          // dtile row stride (floats)

// workspace layout (bytes, 16B-aligned)
#define MSG_OFF   0                      // f32[200000*32] = 25,600,000
#define HEAD_OFF  25600000               // u32[50000]
#define NEXT_OFF  25800000               // u32[200000]
#define WCT_OFF   26600000               // f16[32*552]

using f32x4 = __attribute__((ext_vector_type(4))) float;
using f16x2 = __attribute__((ext_vector_type(2))) _Float16;
using f16x4 = __attribute__((ext_vector_type(4))) _Float16;
using f16x8 = __attribute__((ext_vector_type(8))) _Float16;

__device__ __forceinline__ f16x2 pkrtz(float a, float b) {
    return __builtin_bit_cast(f16x2, __builtin_amdgcn_cvt_pkrtz(a, b));
}

__device__ __forceinline__ void gload_lds16(const void* g, void* l) {
    __builtin_amdgcn_global_load_lds(
        (const __attribute__((address_space(1))) unsigned int*)g,
        (__attribute__((address_space(3))) unsigned int*)l, 16, 0, 0);
}

// ---- D1: wct build (blocks 0..68) + head init (blocks 69..) ----
#define WCT_BLKS 69
__global__ void init_kernel(const float* __restrict__ W_edge,
                            const float* __restrict__ b_edge,
                            _Float16* __restrict__ wct,
                            unsigned* __restrict__ head) {
    int b = blockIdx.x;
    if (b < WCT_BLKS) {
        int gid = b * 256 + threadIdx.x;
        if (gid >= 32 * WCT_ROW) return;
        int n = gid / WCT_ROW;
        int c = gid - n * WCT_ROW;
        float v = 0.0f;
        if (c < 512)      v = W_edge[(c & 15) * 1024 + (c >> 4) * 32 + n];
        else if (c < 544) v = b_edge[(c - 512) * 32 + n];
        wct[gid] = (_Float16)v;
    } else {
        int gid = (b - WCT_BLKS) * 256 + threadIdx.x;
        if (gid < NNODES) head[gid] = 0xFFFFFFFFu;
    }
}

// ---- D2: persistent GEMM blocks; wct staged ONCE, grid-stride over tiles ----
__global__ __launch_bounds__(256, 3) void work_kernel(
    const float* __restrict__ feat, const float* __restrict__ efeat,
    const int* __restrict__ src, const int* __restrict__ dst,
    const _Float16* __restrict__ wct_g,
    float* __restrict__ msg, unsigned* __restrict__ head,
    unsigned* __restrict__ next) {

    __shared__ __align__(16) unsigned short wct_lds[32 * WCT_ROW]; // 35328 B
    __shared__ __align__(16) float dtile[TILE_EDGES * DROW];       // 9216 B

    const int t = threadIdx.x;
    const int lane = t & 63;
    const int wave = t >> 6;
    const int r16 = lane & 15;
    const int g   = lane >> 4;
    const int wbase = wave * 16;

    // Stage WcT global->LDS async once (linear dest, 16B/lane)
    {
        const char* gsrc = (const char*)wct_g;
        char* lbase = (char*)wct_lds;
        #pragma unroll
        for (int c = 0; c < 9; ++c) {
            int chunk = wave + c * 4;
            if (chunk < 35) {
                int boff = (chunk << 10) + lane * 16;
                if (boff < WCT_BYTES) gload_lds16(gsrc + boff, lbase + boff);
            }
        }
    }
    __syncthreads();   // wct resident for the whole block lifetime

    const _Float16* brow0 = (const _Float16*)wct_lds + r16 * WCT_ROW;
    const _Float16* brow1 = (const _Float16*)wct_lds + (16 + r16) * WCT_ROW;

    for (int tile = blockIdx.x; tile < NTILES; tile += WORK_BLOCKS) {
        const int ebase = tile * TILE_EDGES;

        // chain-scatter for this tile's edges (independent; fires early)
        if (t < TILE_EDGES) {
            int e = ebase + t;
            next[e] = atomicExch(&head[dst[e]], (unsigned)e);
        }

        // This lane's A-operand edge: same edge for h and ef
        const int eg = ebase + wbase + r16;

        // ef fragment (16 f16 in 4 words)
        const float* efp = efeat + eg * 16 + (g & 1) * 8;
        float4 e0 = *(const float4*)efp;
        float4 e1 = *(const float4*)(efp + 4);
        f16x2 ef2[4] = { pkrtz(e0.x, e0.y), pkrtz(e0.z, e0.w),
                         pkrtz(e1.x, e1.y), pkrtz(e1.z, e1.w) };

        // h row direct per-lane (4 dup lanes merge in coalescer), packed f16
        unsigned hw[16];
        {
            const int se = src[eg];
            const float4* fp = (const float4*)(feat + se * 32);
            #pragma unroll
            for (int q = 0; q < 8; ++q) {
                float4 v = fp[q];
                hw[2*q+0] = __builtin_bit_cast(unsigned, pkrtz(v.x, v.y));
                hw[2*q+1] = __builtin_bit_cast(unsigned, pkrtz(v.z, v.w));
            }
        }

        // per-s broadcast half2 of h[2s + (g>>1)]
        unsigned hbc[16];
        {
            const bool hi = (g >> 1) & 1;
            #pragma unroll
            for (int s = 0; s < 16; ++s) {
                unsigned x = hi ? (hw[s] >> 16) : (hw[s] & 0xffffu);
                hbc[s] = x | (x << 16);
            }
        }

        f32x4 acc0 = {0.f, 0.f, 0.f, 0.f};
        f32x4 acc1 = {0.f, 0.f, 0.f, 0.f};

        // X[e,c]=h[i]*ef[kk], c=32s+8g+j => i=2s+(g>>1), kk=(g&1)*8+j
        #pragma unroll
        for (int s = 0; s < 16; ++s) {
            const int koff = s * 32 + g * 8;
            f16x8 b0 = *(const f16x8*)(brow0 + koff);
            f16x8 b1 = *(const f16x8*)(brow1 + koff);
            f16x2 hb = __builtin_bit_cast(f16x2, hbc[s]);
            f16x2 p0 = hb * ef2[0], p1 = hb * ef2[1], p2 = hb * ef2[2], p3 = hb * ef2[3];
            f16x4 lo  = __builtin_shufflevector(p0, p1, 0, 1, 2, 3);
            f16x4 hi4 = __builtin_shufflevector(p2, p3, 0, 1, 2, 3);
            f16x8 af  = __builtin_shufflevector(lo, hi4, 0, 1, 2, 3, 4, 5, 6, 7);
            acc0 = __builtin_amdgcn_mfma_f32_16x16x32_f16(af, b0, acc0, 0, 0, 0);
            acc1 = __builtin_amdgcn_mfma_f32_16x16x32_f16(af, b1, acc1, 0, 0, 0);
        }
        {   // bias-extension k-step: X[e,512+i]=h[i]; af = h f16 words 4g..4g+3
            uint4 bwv;
            unsigned* bw = (unsigned*)&bwv;
            #pragma unroll
            for (int j = 0; j < 4; ++j) {
                unsigned lo2 = (g & 1) ? hw[4 + j]  : hw[j];
                unsigned hi2 = (g & 1) ? hw[12 + j] : hw[8 + j];
                bw[j] = (g & 2) ? hi2 : lo2;
            }
            f16x8 af = __builtin_bit_cast(f16x8, bwv);
            const int koff = 512 + g * 8;
            f16x8 b0 = *(const f16x8*)(brow0 + koff);
            f16x8 b1 = *(const f16x8*)(brow1 + koff);
            acc0 = __builtin_amdgcn_mfma_f32_16x16x32_f16(af, b0, acc0, 0, 0, 0);
            acc1 = __builtin_amdgcn_mfma_f32_16x16x32_f16(af, b1, acc1, 0, 0, 0);
        }

        __syncthreads();   // prev iter's dtile reads complete
        {   // D (m89): row = g*4+r (edge in wave tile), col = r16
            const int browD = wbase + g * 4;
            #pragma unroll
            for (int r = 0; r < 4; ++r) {
                dtile[(browD + r) * DROW + r16]      = acc0[r];
                dtile[(browD + r) * DROW + 16 + r16] = acc1[r];
            }
        }
        __syncthreads();

        // Coalesced msg store: thread t -> edge et, 8 consecutive channels
        {
            const int et = t >> 2, q = t & 3;
            const float* drow = dtile + et * DROW + q * 8;
            float4 v0 = *(const float4*)(drow);
            float4 v1 = *(const float4*)(drow + 4);
            float* mp = msg + (ebase + et) * 32 + q * 8;
            *(float4*)(mp)     = v0;
            *(float4*)(mp + 4) = v1;
        }
    }
}

// ---- D3: pull — 8 threads per node share the chain walk ----
__global__ __launch_bounds__(256) void pull_kernel(
    const float* __restrict__ msg, const unsigned* __restrict__ head,
    const unsigned* __restrict__ next, const float* __restrict__ bias,
    float* __restrict__ out) {

    int gid = blockIdx.x * 256 + threadIdx.x;
    if (gid >= NNODES * 8) return;
    int n = gid >> 3, q = gid & 7;

    float4 s = {0.f, 0.f, 0.f, 0.f};
    float degf = 0.0f;

    unsigned e = head[n];
    while (e != 0xFFFFFFFFu) {
        float4 m = *(const float4*)(msg + e * 32 + q * 4);
        s.x += m.x; s.y += m.y; s.z += m.z; s.w += m.w;
        degf += 1.0f;
        e = next[e];
    }

    float inv = 1.0f / fmaxf(degf, 1.0f);
    float4 b = ((const float4*)bias)[q];
    float4 o = { s.x * inv + b.x, s.y * inv + b.y, s.z * inv + b.z, s.w * inv + b.w };
    *(float4*)(out + n * 32 + q * 4) = o;
}

extern "C" void kernel_launch(void* const* d_in, const int* in_sizes, int n_in,
                              void* d_out, int out_size, void* d_ws, size_t ws_size,
                              hipStream_t stream) {
    const float* feat   = (const float*)d_in[0];
    const float* efeat  = (const float*)d_in[1];
    const int*   src    = (const int*)d_in[2];
    const int*   dst    = (const int*)d_in[3];
    const float* W_edge = (const float*)d_in[4];
    const float* b_edge = (const float*)d_in[5];
    const float* bias   = (const float*)d_in[6];

    char* ws = (char*)d_ws;
    float*    msg  = (float*)(ws + MSG_OFF);
    unsigned* head = (unsigned*)(ws + HEAD_OFF);
    unsigned* next = (unsigned*)(ws + NEXT_OFF);
    _Float16* wct  = (_Float16*)(ws + WCT_OFF);
    float*    out  = (float*)d_out;

    init_kernel<<<WCT_BLKS + (NNODES + 255) / 256, 256, 0, stream>>>(
        W_edge, b_edge, wct, head);
    work_kernel<<<WORK_BLOCKS, 256, 0, stream>>>(
        feat, efeat, src, dst, wct, msg, head, next);
    pull_kernel<<<(NNODES * 8 + 255) / 256, 256, 0, stream>>>(
        msg, head, next, bias, out);
}

// Round 10
// 46.443 us; speedup vs baseline: 1.2891x; 1.2891x over previous
//
#include <hip/hip_runtime.h>
#include <hip/hip_bf16.h>

#define NNODES 50000
#define NEDGES 200000
#define WCT_ROW 552                      // f16 units; 1104B row
#define WCT_BYTES (32 * WCT_ROW * 2)     // 35328
#define HROW 40                          // f16 units; 80B row
#define TILE_EDGES 64
#define NTILES (NEDGES / TILE_EDGES)     // 3125
#define CHAIN_BLKS ((NEDGES + 255) / 256) // 782
#define DROW 36                          // dtile row stride (floats)

// workspace layout (bytes, 16B-aligned)
#define MSG_OFF   0                      // f32[200000*32] = 25,600,000 (permuted)
#define HEAD_OFF  25600000               // u32[50000]
#define NEXT_OFF  25800000               // u32[200000]
#define WCT_OFF   26600000               // f16[32*552]

using f32x4 = __attribute__((ext_vector_type(4))) float;
using f16x2 = __attribute__((ext_vector_type(2))) _Float16;
using f16x4 = __attribute__((ext_vector_type(4))) _Float16;
using f16x8 = __attribute__((ext_vector_type(8))) _Float16;

__device__ __forceinline__ f16x2 pkrtz(float a, float b) {
    return __builtin_bit_cast(f16x2, __builtin_amdgcn_cvt_pkrtz(a, b));
}

__device__ __forceinline__ void gload_lds16(const void* g, void* l) {
    __builtin_amdgcn_global_load_lds(
        (const __attribute__((address_space(1))) unsigned int*)g,
        (__attribute__((address_space(3))) unsigned int*)l, 16, 0, 0);
}

// ---- D1: wct build (blocks 0..68) + head init (blocks 69..) ----
#define WCT_BLKS 69
__global__ void init_kernel(const float* __restrict__ W_edge,
                            const float* __restrict__ b_edge,
                            _Float16* __restrict__ wct,
                            unsigned* __restrict__ head) {
    int b = blockIdx.x;
    if (b < WCT_BLKS) {
        int gid = b * 256 + threadIdx.x;
        if (gid >= 32 * WCT_ROW) return;
        int n = gid / WCT_ROW;
        int c = gid - n * WCT_ROW;
        float v = 0.0f;
        if (c < 512)      v = W_edge[(c & 15) * 1024 + (c >> 4) * 32 + n];
        else if (c < 544) v = b_edge[(c - 512) * 32 + n];
        wct[gid] = (_Float16)v;
    } else {
        int gid = (b - WCT_BLKS) * 256 + threadIdx.x;
        if (gid < NNODES) head[gid] = 0xFFFFFFFFu;
    }
}

// ---- D2: GEMM blocks (0..3124) write permuted msg; chain blocks scatter ----
__global__ __launch_bounds__(256, 3) void work_kernel(
    const float* __restrict__ feat, const float* __restrict__ efeat,
    const int* __restrict__ src, const int* __restrict__ dst,
    const _Float16* __restrict__ wct_g,
    float4* __restrict__ msg4, unsigned* __restrict__ head,
    unsigned* __restrict__ next) {

    __shared__ __align__(16) unsigned short wct_lds[32 * WCT_ROW]; // 35328 B
    __shared__ __align__(16) unsigned short h_lds[TILE_EDGES * HROW]; // 5120 B
    __shared__ __align__(16) float dtile[TILE_EDGES * DROW];       // 9216 B

    const int t = threadIdx.x;

    if (blockIdx.x >= NTILES) {
        // chain-scatter: per-dst linked list via atomicExch (200K atomics)
        int e = (blockIdx.x - NTILES) * 256 + t;
        if (e < NEDGES)
            next[e] = atomicExch(&head[dst[e]], (unsigned)e);
        return;
    }

    const int lane = t & 63;
    const int wave = t >> 6;
    const int ebase = blockIdx.x * TILE_EDGES;

    // Stage WcT global->LDS async (linear dest, 16B/lane)
    {
        const char* gsrc = (const char*)wct_g;
        char* lbase = (char*)wct_lds;
        #pragma unroll
        for (int c = 0; c < 9; ++c) {
            int chunk = wave + c * 4;
            if (chunk < 35) {
                int boff = (chunk << 10) + lane * 16;
                if (boff < WCT_BYTES) gload_lds16(gsrc + boff, lbase + boff);
            }
        }
    }

    // Stage gathered h (f32 -> f16) for 64 edges (dense 32B/thread)
    {
        int et = t >> 2, p = t & 3;
        int se = src[ebase + et];
        const float* fp = feat + se * 32 + p * 8;
        float4 a = *(const float4*)fp;
        float4 b = *(const float4*)(fp + 4);
        uint4 hp;
        hp.x = __builtin_bit_cast(unsigned int, pkrtz(a.x, a.y));
        hp.y = __builtin_bit_cast(unsigned int, pkrtz(a.z, a.w));
        hp.z = __builtin_bit_cast(unsigned int, pkrtz(b.x, b.y));
        hp.w = __builtin_bit_cast(unsigned int, pkrtz(b.z, b.w));
        *(uint4*)(void*)(h_lds + et * HROW + p * 8) = hp;
    }

    const int r16 = lane & 15;
    const int g   = lane >> 4;
    const int wbase = wave * 16;
    const int eg = ebase + wbase + r16;

    // ef fragment (independent of LDS; overlaps staging latency)
    const float* efp = efeat + eg * 16 + (g & 1) * 8;
    float4 e0 = *(const float4*)efp;
    float4 e1 = *(const float4*)(efp + 4);
    f16x2 ef2[4] = { pkrtz(e0.x, e0.y), pkrtz(e0.z, e0.w),
                     pkrtz(e1.x, e1.y), pkrtz(e1.z, e1.w) };

    __syncthreads();   // drains global_load_lds + ds_writes

    // h row -> regs; per-s broadcast half2 of h[2s + (g>>1)]
    unsigned int hbc[16];
    f16x8 af_bias;
    {
        const uint4* hrow = (const uint4*)(void*)(h_lds + (wbase + r16) * HROW);
        unsigned int hw[16];
        #pragma unroll
        for (int q = 0; q < 4; ++q) {
            uint4 v = hrow[q];
            hw[q*4+0] = v.x; hw[q*4+1] = v.y; hw[q*4+2] = v.z; hw[q*4+3] = v.w;
        }
        const bool hi = (g >> 1) & 1;
        #pragma unroll
        for (int s = 0; s < 16; ++s) {
            unsigned int x = hi ? (hw[s] >> 16) : (hw[s] & 0xffffu);
            hbc[s] = x | (x << 16);
        }
        af_bias = *(const f16x8*)(void*)((const _Float16*)h_lds + (wbase + r16) * HROW + g * 8);
    }

    const _Float16* brow0 = (const _Float16*)wct_lds + r16 * WCT_ROW;
    const _Float16* brow1 = (const _Float16*)wct_lds + (16 + r16) * WCT_ROW;

    f32x4 acc0 = {0.f, 0.f, 0.f, 0.f};
    f32x4 acc1 = {0.f, 0.f, 0.f, 0.f};

    // X[e,c]=h[i]*ef[kk], c=32s+8g+j => i=2s+(g>>1), kk=(g&1)*8+j
    #pragma unroll
    for (int s = 0; s < 16; ++s) {
        const int koff = s * 32 + g * 8;
        f16x8 b0 = *(const f16x8*)(brow0 + koff);
        f16x8 b1 = *(const f16x8*)(brow1 + koff);
        f16x2 hb = __builtin_bit_cast(f16x2, hbc[s]);
        f16x2 p0 = hb * ef2[0], p1 = hb * ef2[1], p2 = hb * ef2[2], p3 = hb * ef2[3];
        f16x4 lo  = __builtin_shufflevector(p0, p1, 0, 1, 2, 3);
        f16x4 hi4 = __builtin_shufflevector(p2, p3, 0, 1, 2, 3);
        f16x8 af  = __builtin_shufflevector(lo, hi4, 0, 1, 2, 3, 4, 5, 6, 7);
        acc0 = __builtin_amdgcn_mfma_f32_16x16x32_f16(af, b0, acc0, 0, 0, 0);
        acc1 = __builtin_amdgcn_mfma_f32_16x16x32_f16(af, b1, acc1, 0, 0, 0);
    }
    {   // bias-extension k-step: X[e,512+i]=h[i]
        const int koff = 512 + g * 8;
        f16x8 b0 = *(const f16x8*)(brow0 + koff);
        f16x8 b1 = *(const f16x8*)(brow1 + koff);
        acc0 = __builtin_amdgcn_mfma_f32_16x16x32_f16(af_bias, b0, acc0, 0, 0, 0);
        acc1 = __builtin_amdgcn_mfma_f32_16x16x32_f16(af_bias, b1, acc1, 0, 0, 0);
    }

    // D (m89): row = g*4+r (edge in wave tile), col = r16 -> dtile[64][36]
    {
        const int browD = wbase + g * 4;
        #pragma unroll
        for (int r = 0; r < 4; ++r) {
            dtile[(browD + r) * DROW + r16]      = acc0[r];
            dtile[(browD + r) * DROW + 16 + r16] = acc1[r];
        }
    }
    __syncthreads();

    // Dense permuted msg store: slot = tile*512 + store#*256 + t.
    // Slot (store#, t) holds edge el=t>>2, floats (t&3)*8 + store#*4 .. +3.
    // Each store instruction writes a contiguous 4KB span (full lines).
    {
        const int et = t >> 2, q = t & 3;
        const float* drow = dtile + et * DROW + q * 8;
        float4 v0 = *(const float4*)(drow);
        float4 v1 = *(const float4*)(drow + 4);
        float4* mp = msg4 + (size_t)blockIdx.x * 512;
        mp[t]       = v0;
        mp[256 + t] = v1;
    }
}

// ---- D3: pull — 8 threads per node walk the chain, permuted msg reads ----
__global__ __launch_bounds__(256) void pull_kernel(
    const float4* __restrict__ msg4, const unsigned* __restrict__ head,
    const unsigned* __restrict__ next, const float* __restrict__ bias,
    float* __restrict__ out) {

    int gid = blockIdx.x * 256 + threadIdx.x;
    if (gid >= NNODES * 8) return;
    int n = gid >> 3, Q = gid & 7;

    // edge e quad Q lives at slot (e>>6)*512 + (Q&1)*256 + (e&63)*4 + (Q>>1)
    const unsigned qoff = (unsigned)((Q & 1) * 256 + (Q >> 1));

    float4 s = {0.f, 0.f, 0.f, 0.f};
    float degf = 0.0f;

    unsigned e = head[n];
    while (e != 0xFFFFFFFFu) {
        float4 m = msg4[(size_t)(e >> 6) * 512 + qoff + (e & 63) * 4];
        s.x += m.x; s.y += m.y; s.z += m.z; s.w += m.w;
        degf += 1.0f;
        e = next[e];
    }

    float inv = 1.0f / fmaxf(degf, 1.0f);
    float4 b = ((const float4*)bias)[Q];
    float4 o = { s.x * inv + b.x, s.y * inv + b.y, s.z * inv + b.z, s.w * inv + b.w };
    *(float4*)(out + n * 32 + Q * 4) = o;
}

extern "C" void kernel_launch(void* const* d_in, const int* in_sizes, int n_in,
                              void* d_out, int out_size, void* d_ws, size_t ws_size,
                              hipStream_t stream) {
    const float* feat   = (const float*)d_in[0];
    const float* efeat  = (const float*)d_in[1];
    const int*   src    = (const int*)d_in[2];
    const int*   dst    = (const int*)d_in[3];
    const float* W_edge = (const float*)d_in[4];
    const float* b_edge = (const float*)d_in[5];
    const float* bias   = (const float*)d_in[6];

    char* ws = (char*)d_ws;
    float4*   msg4 = (float4*)(ws + MSG_OFF);
    unsigned* head = (unsigned*)(ws + HEAD_OFF);
    unsigned* next = (unsigned*)(ws + NEXT_OFF);
    _Float16* wct  = (_Float16*)(ws + WCT_OFF);
    float*    out  = (float*)d_out;

    init_kernel<<<WCT_BLKS + (NNODES + 255) / 256, 256, 0, stream>>>(
        W_edge, b_edge, wct, head);
    work_kernel<<<NTILES + CHAIN_BLKS, 256, 0, stream>>>(
        feat, efeat, src, dst, wct, msg4, head, next);
    pull_kernel<<<(NNODES * 8 + 255) / 256, 256, 0, stream>>>(
        msg4, head, next, bias, out);
}